// Round 6
// baseline (456.965 us; speedup 1.0000x reference)
//
#include <hip/hip_runtime.h>

#define B_ 2
#define NQ 2048
#define NK 2112
#define CD 1024
#define NH 16
#define HD 64

typedef unsigned short u16;
typedef unsigned int u32;
typedef __attribute__((ext_vector_type(8))) __bf16 bf16x8;
typedef __attribute__((ext_vector_type(4))) float f32x4;

#define GPTR(p) ((const __attribute__((address_space(1))) void*)(p))
#define LPTR(p) ((__attribute__((address_space(3))) void*)(p))
#define GLL16(g, l) __builtin_amdgcn_global_load_lds(GPTR(g), LPTR(l), 16, 0, 0)

__device__ __forceinline__ u16 f2bf(float f) {
  u32 u = __float_as_uint(f);
  u32 r = u + 0x7fffu + ((u >> 16) & 1u);
  return (u16)(r >> 16);
}
// bf(x) | bf(y)<<16 with round-to-nearest-even, no branches
__device__ __forceinline__ u32 pack2bf(float x, float y) {
  u32 a = __float_as_uint(x); a += 0x7fffu + ((a >> 16) & 1u);
  u32 b = __float_as_uint(y); b += 0x7fffu + ((b >> 16) & 1u);
  return __builtin_amdgcn_perm(b, a, 0x07060302u);
}

// (1/sqrt(64)) * log2(e) — folded into the Q projection output
#define SC 0.18033688011112042f
// -log2(theta)/16 and theta^(-1/16)
#define NEGL2T 0.8304820237f
#define FSTEP 0.5623413252f

// ---------- prep: weight transpose+convert only (inputs read as f32 by GEMM) ----
__global__ void prep_kernel(const float* __restrict__ W0, const float* __restrict__ W1,
                            const float* __restrict__ W2, const float* __restrict__ W3,
                            u16* __restrict__ T0, u16* __restrict__ T1,
                            u16* __restrict__ T2, u16* __restrict__ T3) {
  __shared__ u16 tile[32][33];
  int which = blockIdx.y;
  const float* src = (which == 0) ? W0 : (which == 1) ? W1 : (which == 2) ? W2 : W3;
  u16* dst = (which == 0) ? T0 : (which == 1) ? T1 : (which == 2) ? T2 : T3;
  int t = threadIdx.x;
  int r0 = (blockIdx.x >> 5) * 32, c0 = (blockIdx.x & 31) * 32;
  int row = t >> 3, c4 = (t & 7) * 4;
  float4 vv = *(const float4*)&src[(r0 + row) * 1024 + c0 + c4];
  tile[row][c4 + 0] = f2bf(vv.x);
  tile[row][c4 + 1] = f2bf(vv.y);
  tile[row][c4 + 2] = f2bf(vv.z);
  tile[row][c4 + 3] = f2bf(vv.w);
  __syncthreads();
  ushort4 o;
  o.x = tile[c4 + 0][row];
  o.y = tile[c4 + 1][row];
  o.z = tile[c4 + 2][row];
  o.w = tile[c4 + 3][row];
  *(ushort4*)&dst[(c0 + row) * 1024 + r0 + c4] = o;
}

// ---------- fused QKV projection GEMM + RoPE epilogue ----------
// A read as f32 directly (in-register cvt during staging); W via GLL16.
// 128x128 tile, BK=32, 3 blocks/CU. z=0: Q (C^T, in-lane rope, *SC),
// z=1: K (C^T, rope tok<2048), z=2: V (normal, packed scatter to Vt).
__global__ __launch_bounds__(256, 3) void gemm_qkv(
    const float* __restrict__ qf32, const float* __restrict__ kf32, const float* __restrict__ vf32,
    const u16* __restrict__ wqt, const u16* __restrict__ wkt, const u16* __restrict__ wvt,
    const float* __restrict__ bq, const float* __restrict__ bk, const float* __restrict__ bv,
    u16* __restrict__ Qh, u16* __restrict__ Kh, u16* __restrict__ Vt) {
  __shared__ u16 As[128 * 32];
  __shared__ u16 Bs[128 * 32];
  const int z = blockIdx.z;
  if (z == 0 && blockIdx.y >= 32) return;  // Q has 4096 rows only
  const float* A = (z == 0) ? qf32 : (z == 1) ? kf32 : vf32;
  const u16* Bt = (z == 0) ? wqt : (z == 1) ? wkt : wvt;
  const float* bias = (z == 0) ? bq : (z == 1) ? bk : bv;
  const int BR = (z == 0) ? NQ : NK;  // rows per batch

  const int t = threadIdx.x;
  const int lane = t & 63, w = t >> 6;
  const int lc = lane & 15, lq = lane >> 4;
  const int m0 = blockIdx.y * 128, n0 = blockIdx.x * 128;
  const int wm = (w >> 1) * 64, wn = (w & 1) * 64;
  f32x4 acc[4][4] = {};
  const float* ga = A + (m0 + (t >> 2)) * 1024 + (t & 3) * 8;
  const u16* gb = Bt + (n0 + (t >> 2)) * 1024 + (t & 3) * 8;
  u16* sa = &As[(t >> 2) * 32 + (t & 3) * 8];
  char* lB = (char*)Bs + w * 1024;
  const bool swap = (z < 2);

  // pipeline regs: this tile's A rows (r, r+64), 8 f32 each
  float4 a0 = *(const float4*)(ga);
  float4 a1 = *(const float4*)(ga + 4);
  float4 a2 = *(const float4*)(ga + 64 * 1024);
  float4 a3 = *(const float4*)(ga + 64 * 1024 + 4);

  for (int k0 = 0; k0 < 1024; k0 += 32) {
    if (k0) __syncthreads();
    {
      uint4 p0, p1;
      p0.x = pack2bf(a0.x, a0.y); p0.y = pack2bf(a0.z, a0.w);
      p0.z = pack2bf(a1.x, a1.y); p0.w = pack2bf(a1.z, a1.w);
      p1.x = pack2bf(a2.x, a2.y); p1.y = pack2bf(a2.z, a2.w);
      p1.z = pack2bf(a3.x, a3.y); p1.w = pack2bf(a3.z, a3.w);
      *(uint4*)sa = p0;
      *(uint4*)(sa + 64 * 32) = p1;
    }
    GLL16(gb + k0, lB);
    GLL16(gb + 64 * 1024 + k0, lB + 4096);
    if (k0 + 32 < 1024) {  // prefetch next A chunk, in flight through MFMA phase
      a0 = *(const float4*)(ga + k0 + 32);
      a1 = *(const float4*)(ga + k0 + 36);
      a2 = *(const float4*)(ga + 64 * 1024 + k0 + 32);
      a3 = *(const float4*)(ga + 64 * 1024 + k0 + 36);
    }
    __syncthreads();
    bf16x8 af[4], bf[4];
#pragma unroll
    for (int i = 0; i < 4; ++i) {
      af[i] = *(const bf16x8*)&As[(wm + i * 16 + lc) * 32 + lq * 8];
      bf[i] = *(const bf16x8*)&Bs[(wn + i * 16 + lc) * 32 + lq * 8];
    }
    if (swap) {
#pragma unroll
      for (int mi = 0; mi < 4; ++mi)
#pragma unroll
        for (int ni = 0; ni < 4; ++ni)
          acc[mi][ni] = __builtin_amdgcn_mfma_f32_16x16x32_bf16(bf[ni], af[mi], acc[mi][ni], 0, 0, 0);
    } else {
#pragma unroll
      for (int mi = 0; mi < 4; ++mi)
#pragma unroll
        for (int ni = 0; ni < 4; ++ni)
          acc[mi][ni] = __builtin_amdgcn_mfma_f32_16x16x32_bf16(af[mi], bf[ni], acc[mi][ni], 0, 0, 0);
    }
  }

  if (swap) {
    // C^T layout: lane holds row = m0+wm+mi*16+lc, cols cb..cb+3 (in-lane rope pairs)
    u16* Out = (z == 0) ? Qh : Kh;
    const bool isQ = (z == 0);
#pragma unroll
    for (int ni = 0; ni < 4; ++ni) {
      int cb = n0 + wn + ni * 16 + lq * 4;
      float4 bv4 = *(const float4*)&bias[cb];
      int jj = (ni * 8 + lq * 2) & 15;  // pair idx mod 16 (ni<2: x-freqs, ni>=2: y-freqs)
      bool jl = ni < 2;
      float f0 = exp2f((float)jj * -NEGL2T);
      float f1 = f0 * FSTEP;
#pragma unroll
      for (int mi = 0; mi < 4; ++mi) {
        int row = m0 + wm + mi * 16 + lc;
        int bb = row >= BR ? 1 : 0;
        int tok = row - bb * BR;
        float v0 = acc[mi][ni][0] + bv4.x;
        float v1 = acc[mi][ni][1] + bv4.y;
        float v2 = acc[mi][ni][2] + bv4.z;
        float v3 = acc[mi][ni][3] + bv4.w;
        uint2 pk;
        if (isQ || tok < 2048) {
          float pos = jl ? (float)(tok & 63) : (float)(tok >> 6);
          float s0, c0, s1, c1;
          __sincosf(pos * f0, &s0, &c0);
          __sincosf(pos * f1, &s1, &c1);
          float o0 = v0 * c0 - v1 * s0, o1 = v0 * s0 + v1 * c0;
          float o2 = v2 * c1 - v3 * s1, o3 = v2 * s1 + v3 * c1;
          if (isQ) { o0 *= SC; o1 *= SC; o2 *= SC; o3 *= SC; }
          pk.x = (u32)f2bf(o0) | ((u32)f2bf(o1) << 16);
          pk.y = (u32)f2bf(o2) | ((u32)f2bf(o3) << 16);
        } else {
          pk.x = (u32)f2bf(v0) | ((u32)f2bf(v1) << 16);
          pk.y = (u32)f2bf(v2) | ((u32)f2bf(v3) << 16);
        }
        *(uint2*)&Out[row * 1024 + cb] = pk;
      }
    }
  } else {
    // V: normal layout: lane holds col, 4 consecutive toks -> one uint2 into Vt
#pragma unroll
    for (int ni = 0; ni < 4; ++ni) {
      int col = n0 + wn + ni * 16 + lc;
      float bv = bias[col];
      int hh = col >> 6, dd = col & 63;
#pragma unroll
      for (int mi = 0; mi < 4; ++mi) {
        int row0 = m0 + wm + mi * 16 + lq * 4;
        int bb = row0 >= NK ? 1 : 0;
        int tok0 = row0 - bb * NK;  // 4-row group never straddles the batch boundary
        uint2 pk;
        pk.x = pack2bf(acc[mi][ni][0] + bv, acc[mi][ni][1] + bv);
        pk.y = pack2bf(acc[mi][ni][2] + bv, acc[mi][ni][3] + bv);
        *(uint2*)&Vt[((bb * NH + hh) * HD + dd) * NK + tok0] = pk;
      }
    }
  }
}

// ---------- O projection: 128x64 tile, swapped MFMA, f32x4 out ----------
__global__ __launch_bounds__(256, 2) void gemm_o(const u16* __restrict__ A,
                                                 const u16* __restrict__ Bt,
                                                 const float* __restrict__ bias,
                                                 float* __restrict__ Cout) {
  __shared__ u16 As[128 * 32];
  __shared__ u16 Bs[64 * 32];
  const int t = threadIdx.x;
  const int lane = t & 63, w = t >> 6;
  const int lc = lane & 15, lq = lane >> 4;
  const int m0 = blockIdx.y * 128, n0 = blockIdx.x * 64;
  const int wm = (w >> 1) * 64, wn = (w & 1) * 32;
  f32x4 acc[4][2] = {};
  const u16* ga = A + (m0 + (t >> 2)) * 1024 + (t & 3) * 8;
  const u16* gb = Bt + (n0 + (t >> 2)) * 1024 + (t & 3) * 8;
  char* lA = (char*)As + w * 1024;
  char* lB = (char*)Bs + w * 1024;
  for (int k0 = 0; k0 < 1024; k0 += 32) {
    if (k0) __syncthreads();
    GLL16(ga + k0, lA);
    GLL16(ga + 64 * 1024 + k0, lA + 4096);
    GLL16(gb + k0, lB);  // 64 rows of B^T strip, one round
    __syncthreads();
    bf16x8 af[4], bf[2];
#pragma unroll
    for (int i = 0; i < 4; ++i)
      af[i] = *(const bf16x8*)&As[(wm + i * 16 + lc) * 32 + lq * 8];
#pragma unroll
    for (int i = 0; i < 2; ++i)
      bf[i] = *(const bf16x8*)&Bs[(wn + i * 16 + lc) * 32 + lq * 8];
#pragma unroll
    for (int mi = 0; mi < 4; ++mi)
#pragma unroll
      for (int ni = 0; ni < 2; ++ni)
        acc[mi][ni] = __builtin_amdgcn_mfma_f32_16x16x32_bf16(bf[ni], af[mi], acc[mi][ni], 0, 0, 0);
  }
#pragma unroll
  for (int ni = 0; ni < 2; ++ni) {
    int cb = n0 + wn + ni * 16 + lq * 4;
    float4 bv4 = *(const float4*)&bias[cb];
#pragma unroll
    for (int mi = 0; mi < 4; ++mi) {
      int row = m0 + wm + mi * 16 + lc;
      float4 o;
      o.x = acc[mi][ni][0] + bv4.x;
      o.y = acc[mi][ni][1] + bv4.y;
      o.z = acc[mi][ni][2] + bv4.z;
      o.w = acc[mi][ni][3] + bv4.w;
      *(float4*)&Cout[row * 1024 + cb] = o;
    }
  }
}

// ---------- flash attention: no-max softmax, S^T P-writes, K/V LDS double-buffer
// One barrier per K-tile; tile j+1's global loads are in flight through the whole
// compute phase and stored to the idle buffer afterwards (vmcnt wait hidden).
#define LSTR 72
__global__ __launch_bounds__(256, 2) void attn_kernel(const u16* __restrict__ Qh,
                                                      const u16* __restrict__ Kh,
                                                      const u16* __restrict__ Vt,
                                                      u16* __restrict__ AO) {
  __shared__ u16 QPs[128 * LSTR];      // Q staging, then P[q][key] (wave-private rows)
  __shared__ u16 Ks[2 * 64 * LSTR];    // double-buffered
  __shared__ u16 Vs[2 * 64 * LSTR];    // transposed: [dd][key]
  const int t = threadIdx.x;
  const int lane = t & 63, w = t >> 6;
  const int lc = lane & 15, lq = lane >> 4;
  const int rr = lane >> 3, s = lane & 7;
  const int qt = blockIdx.x, h = blockIdx.y, b = blockIdx.z;

  {
    const u16* gq = Qh + (b * NQ + qt * 128 + w * 32 + rr) * CD + h * HD + s * 8;
    u16* lqp = &QPs[(w * 32 + rr) * LSTR + s * 8];
#pragma unroll
    for (int i = 0; i < 4; ++i)
      *(uint4*)(lqp + i * 8 * LSTR) = *(const uint4*)(gq + i * 8 * CD);
  }
  bf16x8 qf[2][2];
#pragma unroll
  for (int ni = 0; ni < 2; ++ni)
#pragma unroll
    for (int kk = 0; kk < 2; ++kk)
      qf[ni][kk] = *(const bf16x8*)&QPs[(w * 32 + ni * 16 + lc) * LSTR + kk * 32 + lq * 8];

  bf16x8 ones;
  {
    u32* op = (u32*)&ones;
    op[0] = op[1] = op[2] = op[3] = 0x3F803F80u;  // bf16 1.0 pairs
  }

  const u16* gK = Kh + (b * NK + w * 16 + rr) * CD + h * HD + s * 8;
  const u16* gV = Vt + ((b * NH + h) * HD + w * 16 + rr) * NK + s * 8;
  const int sk0 = (w * 16 + rr) * LSTR + s * 8;      // staging offsets in a buffer
  const int sk1 = (w * 16 + 8 + rr) * LSTR + s * 8;

  // prologue: tile0 -> buf0; issue tile1 loads
  uint4 kreg0 = *(const uint4*)(gK);
  uint4 kreg1 = *(const uint4*)(gK + 8 * CD);
  uint4 vreg0 = *(const uint4*)(gV);
  uint4 vreg1 = *(const uint4*)(gV + 8 * NK);
  *(uint4*)&Ks[sk0] = kreg0;
  *(uint4*)&Ks[sk1] = kreg1;
  *(uint4*)&Vs[sk0] = vreg0;
  *(uint4*)&Vs[sk1] = vreg1;
  kreg0 = *(const uint4*)(gK + 64 * CD);
  kreg1 = *(const uint4*)(gK + 64 * CD + 8 * CD);
  vreg0 = *(const uint4*)(gV + 64);
  vreg1 = *(const uint4*)(gV + 8 * NK + 64);
  __syncthreads();

  f32x4 oacc[2][4] = {};
  f32x4 lacc[2] = {};
  int p = 0;

  for (int j0 = 0; j0 < NK; j0 += 64) {
    const u16* Kc = &Ks[p * 64 * LSTR];
    const u16* Vc = &Vs[p * 64 * LSTR];

    f32x4 st[2][4] = {};
#pragma unroll
    for (int mi = 0; mi < 4; ++mi) {
      bf16x8 k0f = *(const bf16x8*)&Kc[(mi * 16 + lc) * LSTR + lq * 8];
      bf16x8 k1f = *(const bf16x8*)&Kc[(mi * 16 + lc) * LSTR + 32 + lq * 8];
#pragma unroll
      for (int ni = 0; ni < 2; ++ni) {
        st[ni][mi] = __builtin_amdgcn_mfma_f32_16x16x32_bf16(k0f, qf[ni][0], st[ni][mi], 0, 0, 0);
        st[ni][mi] = __builtin_amdgcn_mfma_f32_16x16x32_bf16(k1f, qf[ni][1], st[ni][mi], 0, 0, 0);
      }
    }
#pragma unroll
    for (int ni = 0; ni < 2; ++ni)
#pragma unroll
      for (int mi = 0; mi < 4; ++mi) {
        u32 e0 = __float_as_uint(__builtin_amdgcn_exp2f(st[ni][mi][0]));
        u32 e1 = __float_as_uint(__builtin_amdgcn_exp2f(st[ni][mi][1]));
        u32 e2 = __float_as_uint(__builtin_amdgcn_exp2f(st[ni][mi][2]));
        u32 e3 = __float_as_uint(__builtin_amdgcn_exp2f(st[ni][mi][3]));
        uint2 pk;
        pk.x = __builtin_amdgcn_perm(e1 + 0x8000u, e0 + 0x8000u, 0x07060302u);
        pk.y = __builtin_amdgcn_perm(e3 + 0x8000u, e2 + 0x8000u, 0x07060302u);
        *(uint2*)&QPs[(w * 32 + ni * 16 + lc) * LSTR + mi * 16 + lq * 4] = pk;
      }
#pragma unroll
    for (int kc = 0; kc < 2; ++kc) {
      bf16x8 pf[2], vf[4];
#pragma unroll
      for (int ni = 0; ni < 2; ++ni)
        pf[ni] = *(const bf16x8*)&QPs[(w * 32 + ni * 16 + lc) * LSTR + kc * 32 + lq * 8];
#pragma unroll
      for (int di = 0; di < 4; ++di)
        vf[di] = *(const bf16x8*)&Vs[p * 64 * LSTR + (di * 16 + lc) * LSTR + kc * 32 + lq * 8];
#pragma unroll
      for (int ni = 0; ni < 2; ++ni) {
#pragma unroll
        for (int di = 0; di < 4; ++di)
          oacc[ni][di] = __builtin_amdgcn_mfma_f32_16x16x32_bf16(pf[ni], vf[di], oacc[ni][di], 0, 0, 0);
        lacc[ni] = __builtin_amdgcn_mfma_f32_16x16x32_bf16(pf[ni], ones, lacc[ni], 0, 0, 0);
      }
    }
    (void)Vc;

    if (j0 + 64 < NK) {
      // store tile j+1 into the idle buffer (vmcnt wait was hidden by compute)
      u16* Kn = &Ks[(p ^ 1) * 64 * LSTR];
      u16* Vn = &Vs[(p ^ 1) * 64 * LSTR];
      *(uint4*)&Kn[sk0] = kreg0;
      *(uint4*)&Kn[sk1] = kreg1;
      *(uint4*)&Vn[sk0] = vreg0;
      *(uint4*)&Vn[sk1] = vreg1;
      if (j0 + 128 < NK) {  // issue tile j+2 loads
        kreg0 = *(const uint4*)(gK + (j0 + 128) * CD);
        kreg1 = *(const uint4*)(gK + (j0 + 128) * CD + 8 * CD);
        vreg0 = *(const uint4*)(gV + j0 + 128);
        vreg1 = *(const uint4*)(gV + 8 * NK + j0 + 128);
      }
    }
    __syncthreads();
    p ^= 1;
  }
#pragma unroll
  for (int ni = 0; ni < 2; ++ni)
#pragma unroll
    for (int r = 0; r < 4; ++r) {
      float inv = 1.0f / lacc[ni][r];
#pragma unroll
      for (int di = 0; di < 4; ++di) {
        int row = qt * 128 + w * 32 + ni * 16 + lq * 4 + r;
        int col = h * HD + di * 16 + lc;
        AO[(b * NQ + row) * CD + col] = f2bf(oacc[ni][di][r] * inv);
      }
    }
}

extern "C" void kernel_launch(void* const* d_in, const int* in_sizes, int n_in,
                              void* d_out, int out_size, void* d_ws, size_t ws_size,
                              hipStream_t stream) {
  const float* q  = (const float*)d_in[0];
  const float* k  = (const float*)d_in[1];
  const float* v  = (const float*)d_in[2];
  const float* Wq = (const float*)d_in[3];
  const float* bq = (const float*)d_in[4];
  const float* Wk = (const float*)d_in[5];
  const float* bk = (const float*)d_in[6];
  const float* Wv = (const float*)d_in[7];
  const float* bv = (const float*)d_in[8];
  const float* Wo = (const float*)d_in[9];
  const float* bo = (const float*)d_in[10];

  char* ws = (char*)d_ws;
  size_t off = 0;
  auto alloc = [&](size_t bytes) {
    char* p = ws + off;
    off += (bytes + 255) & ~(size_t)255;
    return p;
  };
  u16* wqt = (u16*)alloc((size_t)CD * CD * 2);
  u16* wkt = (u16*)alloc((size_t)CD * CD * 2);
  u16* wvt = (u16*)alloc((size_t)CD * CD * 2);
  u16* wot = (u16*)alloc((size_t)CD * CD * 2);
  u16* Qh  = (u16*)alloc((size_t)B_ * NQ * CD * 2);
  u16* Kh  = (u16*)alloc((size_t)B_ * NK * CD * 2);
  u16* Vt  = (u16*)alloc((size_t)B_ * NK * CD * 2);
  u16* AO  = (u16*)alloc((size_t)B_ * NQ * CD * 2);

  prep_kernel<<<dim3(1024, 4), 256, 0, stream>>>(Wq, Wk, Wv, Wo, wqt, wkt, wvt, wot);
  gemm_qkv<<<dim3(8, 33, 3), 256, 0, stream>>>(q, k, v, wqt, wkt, wvt, bq, bk, bv, Qh, Kh, Vt);
  attn_kernel<<<dim3(16, NH, B_), 256, 0, stream>>>(Qh, Kh, Vt, AO);
  gemm_o<<<dim3(16, 32), 256, 0, stream>>>(AO, wot, bo, (float*)d_out);
}

// Round 7
// 303.075 us; speedup vs baseline: 1.5078x; 1.5078x over previous
//
#include <hip/hip_runtime.h>

#define B_ 2
#define NQ 2048
#define NK 2112
#define CD 1024
#define NH 16
#define HD 64

typedef unsigned short u16;
typedef unsigned int u32;
typedef __attribute__((ext_vector_type(8))) __bf16 bf16x8;
typedef __attribute__((ext_vector_type(4))) float f32x4;

#define GPTR(p) ((const __attribute__((address_space(1))) void*)(p))
#define LPTR(p) ((__attribute__((address_space(3))) void*)(p))
#define GLL16(g, l) __builtin_amdgcn_global_load_lds(GPTR(g), LPTR(l), 16, 0, 0)

__device__ __forceinline__ u16 f2bf(float f) {
  u32 u = __float_as_uint(f);
  u32 r = u + 0x7fffu + ((u >> 16) & 1u);
  return (u16)(r >> 16);
}
// bf(x) | bf(y)<<16 with round-to-nearest-even
__device__ __forceinline__ u32 pack2bf(float x, float y) {
  u32 a = __float_as_uint(x); a += 0x7fffu + ((a >> 16) & 1u);
  u32 b = __float_as_uint(y); b += 0x7fffu + ((b >> 16) & 1u);
  return __builtin_amdgcn_perm(b, a, 0x07060302u);
}

// (1/sqrt(64)) * log2(e) — folded into the Q projection output
#define SC 0.18033688011112042f
// -log2(theta)/16 and theta^(-1/16)
#define NEGL2T 0.8304820237f
#define FSTEP 0.5623413252f

// ---------- prep: f32->bf16 convert (y=0..2) + weight transpose (y=3) ----------
__global__ void prep_kernel(const float* __restrict__ q, const float* __restrict__ k,
                            const float* __restrict__ v, u16* __restrict__ qb,
                            u16* __restrict__ kb, u16* __restrict__ vb,
                            const float* __restrict__ W0, const float* __restrict__ W1,
                            const float* __restrict__ W2, const float* __restrict__ W3,
                            u16* __restrict__ T0, u16* __restrict__ T1,
                            u16* __restrict__ T2, u16* __restrict__ T3) {
  __shared__ u16 tile[32][33];
  int y = blockIdx.y;
  int t = threadIdx.x;
  if (y < 3) {
    const float* src = (y == 0) ? q : (y == 1) ? k : v;
    u16* dst = (y == 0) ? qb : (y == 1) ? kb : vb;
    int n4 = (y == 0) ? (B_ * NQ * CD / 4) : (B_ * NK * CD / 4);
    int i = blockIdx.x * 256 + t;
    if (i >= n4) return;
    float4 vv = ((const float4*)src)[i];
    ushort4 o;
    o.x = f2bf(vv.x); o.y = f2bf(vv.y); o.z = f2bf(vv.z); o.w = f2bf(vv.w);
    ((ushort4*)dst)[i] = o;
  } else {
    int x = blockIdx.x;
    if (x >= 4096) return;
    int which = x >> 10, xy = x & 1023;
    const float* src = (which == 0) ? W0 : (which == 1) ? W1 : (which == 2) ? W2 : W3;
    u16* dst = (which == 0) ? T0 : (which == 1) ? T1 : (which == 2) ? T2 : T3;
    int r0 = (xy >> 5) * 32, c0 = (xy & 31) * 32;
    int row = t >> 3, c4 = (t & 7) * 4;
    float4 vv = *(const float4*)&src[(r0 + row) * 1024 + c0 + c4];
    tile[row][c4 + 0] = f2bf(vv.x);
    tile[row][c4 + 1] = f2bf(vv.y);
    tile[row][c4 + 2] = f2bf(vv.z);
    tile[row][c4 + 3] = f2bf(vv.w);
    __syncthreads();
    ushort4 o;
    o.x = tile[c4 + 0][row];
    o.y = tile[c4 + 1][row];
    o.z = tile[c4 + 2][row];
    o.w = tile[c4 + 3][row];
    *(ushort4*)&dst[(c0 + row) * 1024 + r0 + c4] = o;
  }
}

// ---------- fused QKV projection GEMM + RoPE epilogue ----------
// Round-5 register footprint (bf16 A via GLL16, no f32 prefetch regs) so that
// __launch_bounds__(256,3) fits without spills: 88 VGPR + 64 AGPR = 152 <= 170.
// 3 blocks/CU -> 792 blocks in 1.03 dispatch waves (was 1.55 at 2/CU).
__global__ __launch_bounds__(256, 3) void gemm_qkv(
    const u16* __restrict__ qb, const u16* __restrict__ kb, const u16* __restrict__ vb,
    const u16* __restrict__ wqt, const u16* __restrict__ wkt, const u16* __restrict__ wvt,
    const float* __restrict__ bq, const float* __restrict__ bk, const float* __restrict__ bv,
    u16* __restrict__ Qh, u16* __restrict__ Kh, u16* __restrict__ Vt) {
  __shared__ u16 As[128 * 32];
  __shared__ u16 Bs[128 * 32];
  const int z = blockIdx.z;
  if (z == 0 && blockIdx.y >= 32) return;  // Q has 4096 rows only
  const u16* A = (z == 0) ? qb : (z == 1) ? kb : vb;
  const u16* Bt = (z == 0) ? wqt : (z == 1) ? wkt : wvt;
  const float* bias = (z == 0) ? bq : (z == 1) ? bk : bv;
  const int BR = (z == 0) ? NQ : NK;  // rows per batch

  const int t = threadIdx.x;
  const int lane = t & 63, w = t >> 6;
  const int lc = lane & 15, lq = lane >> 4;
  const int m0 = blockIdx.y * 128, n0 = blockIdx.x * 128;
  const int wm = (w >> 1) * 64, wn = (w & 1) * 64;
  f32x4 acc[4][4] = {};
  const u16* ga = A + (m0 + (t >> 2)) * 1024 + (t & 3) * 8;
  const u16* gb = Bt + (n0 + (t >> 2)) * 1024 + (t & 3) * 8;
  char* lA = (char*)As + w * 1024;
  char* lB = (char*)Bs + w * 1024;
  const bool swap = (z < 2);
  for (int k0 = 0; k0 < 1024; k0 += 32) {
    if (k0) __syncthreads();
    GLL16(ga + k0, lA);
    GLL16(ga + 64 * 1024 + k0, lA + 4096);
    GLL16(gb + k0, lB);
    GLL16(gb + 64 * 1024 + k0, lB + 4096);
    __syncthreads();
    bf16x8 af[4], bf[4];
#pragma unroll
    for (int i = 0; i < 4; ++i) {
      af[i] = *(const bf16x8*)&As[(wm + i * 16 + lc) * 32 + lq * 8];
      bf[i] = *(const bf16x8*)&Bs[(wn + i * 16 + lc) * 32 + lq * 8];
    }
    if (swap) {
      // acc[mi][ni] = (W row ni-block) x (A row mi-block): C^T layout
#pragma unroll
      for (int mi = 0; mi < 4; ++mi)
#pragma unroll
        for (int ni = 0; ni < 4; ++ni)
          acc[mi][ni] = __builtin_amdgcn_mfma_f32_16x16x32_bf16(bf[ni], af[mi], acc[mi][ni], 0, 0, 0);
    } else {
#pragma unroll
      for (int mi = 0; mi < 4; ++mi)
#pragma unroll
        for (int ni = 0; ni < 4; ++ni)
          acc[mi][ni] = __builtin_amdgcn_mfma_f32_16x16x32_bf16(af[mi], bf[ni], acc[mi][ni], 0, 0, 0);
    }
  }

  if (swap) {
    // C^T layout: lane holds row = m0+wm+mi*16+lc, cols cb..cb+3 (in-lane rope pairs)
    u16* Out = (z == 0) ? Qh : Kh;
    const bool isQ = (z == 0);
#pragma unroll
    for (int ni = 0; ni < 4; ++ni) {
      int cb = n0 + wn + ni * 16 + lq * 4;
      float4 bv4 = *(const float4*)&bias[cb];
      int jj = (ni * 8 + lq * 2) & 15;  // pair idx mod 16 (ni<2: x-freqs, ni>=2: y-freqs)
      bool jl = ni < 2;
      float f0 = exp2f((float)jj * -NEGL2T);
      float f1 = f0 * FSTEP;
#pragma unroll
      for (int mi = 0; mi < 4; ++mi) {
        int row = m0 + wm + mi * 16 + lc;
        int bb = row >= BR ? 1 : 0;
        int tok = row - bb * BR;
        float v0 = acc[mi][ni][0] + bv4.x;
        float v1 = acc[mi][ni][1] + bv4.y;
        float v2 = acc[mi][ni][2] + bv4.z;
        float v3 = acc[mi][ni][3] + bv4.w;
        uint2 pk;
        if (isQ || tok < 2048) {
          float pos = jl ? (float)(tok & 63) : (float)(tok >> 6);
          float s0, c0, s1, c1;
          __sincosf(pos * f0, &s0, &c0);
          __sincosf(pos * f1, &s1, &c1);
          float o0 = v0 * c0 - v1 * s0, o1 = v0 * s0 + v1 * c0;
          float o2 = v2 * c1 - v3 * s1, o3 = v2 * s1 + v3 * c1;
          if (isQ) { o0 *= SC; o1 *= SC; o2 *= SC; o3 *= SC; }
          pk.x = pack2bf(o0, o1);
          pk.y = pack2bf(o2, o3);
        } else {
          pk.x = pack2bf(v0, v1);
          pk.y = pack2bf(v2, v3);
        }
        *(uint2*)&Out[row * 1024 + cb] = pk;
      }
    }
  } else {
    // V: normal layout: lane holds col, 4 consecutive toks -> one uint2 into Vt
#pragma unroll
    for (int ni = 0; ni < 4; ++ni) {
      int col = n0 + wn + ni * 16 + lc;
      float bv = bias[col];
      int hh = col >> 6, dd = col & 63;
#pragma unroll
      for (int mi = 0; mi < 4; ++mi) {
        int row0 = m0 + wm + mi * 16 + lq * 4;
        int bb = row0 >= NK ? 1 : 0;
        int tok0 = row0 - bb * NK;  // 4-row group never straddles the batch boundary
        uint2 pk;
        pk.x = pack2bf(acc[mi][ni][0] + bv, acc[mi][ni][1] + bv);
        pk.y = pack2bf(acc[mi][ni][2] + bv, acc[mi][ni][3] + bv);
        *(uint2*)&Vt[((bb * NH + hh) * HD + dd) * NK + tok0] = pk;
      }
    }
  }
}

// ---------- O projection: 128x64 tile (512 blocks = 2/CU), swapped MFMA, f32x4 out --
__global__ __launch_bounds__(256, 2) void gemm_o(const u16* __restrict__ A,
                                                 const u16* __restrict__ Bt,
                                                 const float* __restrict__ bias,
                                                 float* __restrict__ Cout) {
  __shared__ u16 As[128 * 32];
  __shared__ u16 Bs[64 * 32];
  const int t = threadIdx.x;
  const int lane = t & 63, w = t >> 6;
  const int lc = lane & 15, lq = lane >> 4;
  const int m0 = blockIdx.y * 128, n0 = blockIdx.x * 64;
  const int wm = (w >> 1) * 64, wn = (w & 1) * 32;
  f32x4 acc[4][2] = {};
  const u16* ga = A + (m0 + (t >> 2)) * 1024 + (t & 3) * 8;
  const u16* gb = Bt + (n0 + (t >> 2)) * 1024 + (t & 3) * 8;
  char* lA = (char*)As + w * 1024;
  char* lB = (char*)Bs + w * 1024;
  for (int k0 = 0; k0 < 1024; k0 += 32) {
    if (k0) __syncthreads();
    GLL16(ga + k0, lA);
    GLL16(ga + 64 * 1024 + k0, lA + 4096);
    GLL16(gb + k0, lB);  // 64 rows of B^T strip, one round
    __syncthreads();
    bf16x8 af[4], bf[2];
#pragma unroll
    for (int i = 0; i < 4; ++i)
      af[i] = *(const bf16x8*)&As[(wm + i * 16 + lc) * 32 + lq * 8];
#pragma unroll
    for (int i = 0; i < 2; ++i)
      bf[i] = *(const bf16x8*)&Bs[(wn + i * 16 + lc) * 32 + lq * 8];
#pragma unroll
    for (int mi = 0; mi < 4; ++mi)
#pragma unroll
      for (int ni = 0; ni < 2; ++ni)
        acc[mi][ni] = __builtin_amdgcn_mfma_f32_16x16x32_bf16(bf[ni], af[mi], acc[mi][ni], 0, 0, 0);
  }
#pragma unroll
  for (int ni = 0; ni < 2; ++ni) {
    int cb = n0 + wn + ni * 16 + lq * 4;
    float4 bv4 = *(const float4*)&bias[cb];
#pragma unroll
    for (int mi = 0; mi < 4; ++mi) {
      int row = m0 + wm + mi * 16 + lc;
      float4 o;
      o.x = acc[mi][ni][0] + bv4.x;
      o.y = acc[mi][ni][1] + bv4.y;
      o.z = acc[mi][ni][2] + bv4.z;
      o.w = acc[mi][ni][3] + bv4.w;
      *(float4*)&Cout[row * 1024 + cb] = o;
    }
  }
}

// ---------- flash attention: no-max softmax, S^T P-writes, K/V LDS double-buffer
#define LSTR 72
__global__ __launch_bounds__(256, 2) void attn_kernel(const u16* __restrict__ Qh,
                                                      const u16* __restrict__ Kh,
                                                      const u16* __restrict__ Vt,
                                                      u16* __restrict__ AO) {
  __shared__ u16 QPs[128 * LSTR];      // Q staging, then P[q][key] (wave-private rows)
  __shared__ u16 Ks[2 * 64 * LSTR];    // double-buffered
  __shared__ u16 Vs[2 * 64 * LSTR];    // transposed: [dd][key]
  const int t = threadIdx.x;
  const int lane = t & 63, w = t >> 6;
  const int lc = lane & 15, lq = lane >> 4;
  const int rr = lane >> 3, s = lane & 7;
  const int qt = blockIdx.x, h = blockIdx.y, b = blockIdx.z;

  {
    const u16* gq = Qh + (b * NQ + qt * 128 + w * 32 + rr) * CD + h * HD + s * 8;
    u16* lqp = &QPs[(w * 32 + rr) * LSTR + s * 8];
#pragma unroll
    for (int i = 0; i < 4; ++i)
      *(uint4*)(lqp + i * 8 * LSTR) = *(const uint4*)(gq + i * 8 * CD);
  }
  bf16x8 qf[2][2];
#pragma unroll
  for (int ni = 0; ni < 2; ++ni)
#pragma unroll
    for (int kk = 0; kk < 2; ++kk)
      qf[ni][kk] = *(const bf16x8*)&QPs[(w * 32 + ni * 16 + lc) * LSTR + kk * 32 + lq * 8];

  bf16x8 ones;
  {
    u32* op = (u32*)&ones;
    op[0] = op[1] = op[2] = op[3] = 0x3F803F80u;  // bf16 1.0 pairs
  }

  const u16* gK = Kh + (b * NK + w * 16 + rr) * CD + h * HD + s * 8;
  const u16* gV = Vt + ((b * NH + h) * HD + w * 16 + rr) * NK + s * 8;
  const int sk0 = (w * 16 + rr) * LSTR + s * 8;      // staging offsets in a buffer
  const int sk1 = (w * 16 + 8 + rr) * LSTR + s * 8;

  // prologue: tile0 -> buf0; issue tile1 loads
  uint4 kreg0 = *(const uint4*)(gK);
  uint4 kreg1 = *(const uint4*)(gK + 8 * CD);
  uint4 vreg0 = *(const uint4*)(gV);
  uint4 vreg1 = *(const uint4*)(gV + 8 * NK);
  *(uint4*)&Ks[sk0] = kreg0;
  *(uint4*)&Ks[sk1] = kreg1;
  *(uint4*)&Vs[sk0] = vreg0;
  *(uint4*)&Vs[sk1] = vreg1;
  kreg0 = *(const uint4*)(gK + 64 * CD);
  kreg1 = *(const uint4*)(gK + 64 * CD + 8 * CD);
  vreg0 = *(const uint4*)(gV + 64);
  vreg1 = *(const uint4*)(gV + 8 * NK + 64);
  __syncthreads();

  f32x4 oacc[2][4] = {};
  f32x4 lacc[2] = {};
  int p = 0;

  for (int j0 = 0; j0 < NK; j0 += 64) {
    const u16* Kc = &Ks[p * 64 * LSTR];

    f32x4 st[2][4] = {};
#pragma unroll
    for (int mi = 0; mi < 4; ++mi) {
      bf16x8 k0f = *(const bf16x8*)&Kc[(mi * 16 + lc) * LSTR + lq * 8];
      bf16x8 k1f = *(const bf16x8*)&Kc[(mi * 16 + lc) * LSTR + 32 + lq * 8];
#pragma unroll
      for (int ni = 0; ni < 2; ++ni) {
        st[ni][mi] = __builtin_amdgcn_mfma_f32_16x16x32_bf16(k0f, qf[ni][0], st[ni][mi], 0, 0, 0);
        st[ni][mi] = __builtin_amdgcn_mfma_f32_16x16x32_bf16(k1f, qf[ni][1], st[ni][mi], 0, 0, 0);
      }
    }
#pragma unroll
    for (int ni = 0; ni < 2; ++ni)
#pragma unroll
      for (int mi = 0; mi < 4; ++mi) {
        u32 e0 = __float_as_uint(__builtin_amdgcn_exp2f(st[ni][mi][0]));
        u32 e1 = __float_as_uint(__builtin_amdgcn_exp2f(st[ni][mi][1]));
        u32 e2 = __float_as_uint(__builtin_amdgcn_exp2f(st[ni][mi][2]));
        u32 e3 = __float_as_uint(__builtin_amdgcn_exp2f(st[ni][mi][3]));
        uint2 pk;
        pk.x = __builtin_amdgcn_perm(e1 + 0x8000u, e0 + 0x8000u, 0x07060302u);
        pk.y = __builtin_amdgcn_perm(e3 + 0x8000u, e2 + 0x8000u, 0x07060302u);
        *(uint2*)&QPs[(w * 32 + ni * 16 + lc) * LSTR + mi * 16 + lq * 4] = pk;
      }
#pragma unroll
    for (int kc = 0; kc < 2; ++kc) {
      bf16x8 pf[2], vf[4];
#pragma unroll
      for (int ni = 0; ni < 2; ++ni)
        pf[ni] = *(const bf16x8*)&QPs[(w * 32 + ni * 16 + lc) * LSTR + kc * 32 + lq * 8];
#pragma unroll
      for (int di = 0; di < 4; ++di)
        vf[di] = *(const bf16x8*)&Vs[p * 64 * LSTR + (di * 16 + lc) * LSTR + kc * 32 + lq * 8];
#pragma unroll
      for (int ni = 0; ni < 2; ++ni) {
#pragma unroll
        for (int di = 0; di < 4; ++di)
          oacc[ni][di] = __builtin_amdgcn_mfma_f32_16x16x32_bf16(pf[ni], vf[di], oacc[ni][di], 0, 0, 0);
        lacc[ni] = __builtin_amdgcn_mfma_f32_16x16x32_bf16(pf[ni], ones, lacc[ni], 0, 0, 0);
      }
    }

    if (j0 + 64 < NK) {
      // store tile j+1 into the idle buffer (vmcnt wait was hidden by compute)
      u16* Kn = &Ks[(p ^ 1) * 64 * LSTR];
      u16* Vn = &Vs[(p ^ 1) * 64 * LSTR];
      *(uint4*)&Kn[sk0] = kreg0;
      *(uint4*)&Kn[sk1] = kreg1;
      *(uint4*)&Vn[sk0] = vreg0;
      *(uint4*)&Vn[sk1] = vreg1;
      if (j0 + 128 < NK) {  // issue tile j+2 loads
        kreg0 = *(const uint4*)(gK + (j0 + 128) * CD);
        kreg1 = *(const uint4*)(gK + (j0 + 128) * CD + 8 * CD);
        vreg0 = *(const uint4*)(gV + j0 + 128);
        vreg1 = *(const uint4*)(gV + 8 * NK + j0 + 128);
      }
    }
    __syncthreads();
    p ^= 1;
  }
#pragma unroll
  for (int ni = 0; ni < 2; ++ni)
#pragma unroll
    for (int r = 0; r < 4; ++r) {
      float inv = 1.0f / lacc[ni][r];
#pragma unroll
      for (int di = 0; di < 4; ++di) {
        int row = qt * 128 + w * 32 + ni * 16 + lq * 4 + r;
        int col = h * HD + di * 16 + lc;
        AO[(b * NQ + row) * CD + col] = f2bf(oacc[ni][di][r] * inv);
      }
    }
}

extern "C" void kernel_launch(void* const* d_in, const int* in_sizes, int n_in,
                              void* d_out, int out_size, void* d_ws, size_t ws_size,
                              hipStream_t stream) {
  const float* q  = (const float*)d_in[0];
  const float* k  = (const float*)d_in[1];
  const float* v  = (const float*)d_in[2];
  const float* Wq = (const float*)d_in[3];
  const float* bq = (const float*)d_in[4];
  const float* Wk = (const float*)d_in[5];
  const float* bk = (const float*)d_in[6];
  const float* Wv = (const float*)d_in[7];
  const float* bv = (const float*)d_in[8];
  const float* Wo = (const float*)d_in[9];
  const float* bo = (const float*)d_in[10];

  char* ws = (char*)d_ws;
  size_t off = 0;
  auto alloc = [&](size_t bytes) {
    char* p = ws + off;
    off += (bytes + 255) & ~(size_t)255;
    return p;
  };
  u16* qb  = (u16*)alloc((size_t)B_ * NQ * CD * 2);
  u16* kb  = (u16*)alloc((size_t)B_ * NK * CD * 2);
  u16* vb  = (u16*)alloc((size_t)B_ * NK * CD * 2);
  u16* wqt = (u16*)alloc((size_t)CD * CD * 2);
  u16* wkt = (u16*)alloc((size_t)CD * CD * 2);
  u16* wvt = (u16*)alloc((size_t)CD * CD * 2);
  u16* wot = (u16*)alloc((size_t)CD * CD * 2);
  u16* Qh  = (u16*)alloc((size_t)B_ * NQ * CD * 2);
  u16* Kh  = (u16*)alloc((size_t)B_ * NK * CD * 2);
  u16* Vt  = (u16*)alloc((size_t)B_ * NK * CD * 2);
  u16* AO  = (u16*)alloc((size_t)B_ * NQ * CD * 2);

  prep_kernel<<<dim3(4224, 4), 256, 0, stream>>>(q, k, v, qb, kb, vb,
                                                 Wq, Wk, Wv, Wo, wqt, wkt, wvt, wot);
  gemm_qkv<<<dim3(8, 33, 3), 256, 0, stream>>>(qb, kb, vb, wqt, wkt, wvt, bq, bk, bv, Qh, Kh, Vt);
  attn_kernel<<<dim3(16, NH, B_), 256, 0, stream>>>(Qh, Kh, Vt, AO);
  gemm_o<<<dim3(16, 32), 256, 0, stream>>>(AO, wot, bo, (float*)d_out);
}

// Round 8
// 246.561 us; speedup vs baseline: 1.8534x; 1.2292x over previous
//
#include <hip/hip_runtime.h>

#define B_ 2
#define NQ 2048
#define NK 2112
#define CD 1024
#define NH 16
#define HD 64

typedef unsigned short u16;
typedef unsigned int u32;
typedef __attribute__((ext_vector_type(8))) __bf16 bf16x8;
typedef __attribute__((ext_vector_type(4))) float f32x4;

#define GPTR(p) ((const __attribute__((address_space(1))) void*)(p))
#define LPTR(p) ((__attribute__((address_space(3))) void*)(p))
#define GLL16(g, l) __builtin_amdgcn_global_load_lds(GPTR(g), LPTR(l), 16, 0, 0)

__device__ __forceinline__ u16 f2bf(float f) {
  u32 u = __float_as_uint(f);
  u32 r = u + 0x7fffu + ((u >> 16) & 1u);
  return (u16)(r >> 16);
}
// bf(x) | bf(y)<<16 with round-to-nearest-even
__device__ __forceinline__ u32 pack2bf(float x, float y) {
  u32 a = __float_as_uint(x); a += 0x7fffu + ((a >> 16) & 1u);
  u32 b = __float_as_uint(y); b += 0x7fffu + ((b >> 16) & 1u);
  return __builtin_amdgcn_perm(b, a, 0x07060302u);
}

// (1/sqrt(64)) * log2(e) — folded into the Q projection output
#define SC 0.18033688011112042f
// -log2(theta)/16 and theta^(-1/16)
#define NEGL2T 0.8304820237f
#define FSTEP 0.5623413252f

// ---------- prep: f32->bf16 convert (y=0..2) + weight transpose (y=3) ----------
__global__ void prep_kernel(const float* __restrict__ q, const float* __restrict__ k,
                            const float* __restrict__ v, u16* __restrict__ qb,
                            u16* __restrict__ kb, u16* __restrict__ vb,
                            const float* __restrict__ W0, const float* __restrict__ W1,
                            const float* __restrict__ W2, const float* __restrict__ W3,
                            u16* __restrict__ T0, u16* __restrict__ T1,
                            u16* __restrict__ T2, u16* __restrict__ T3) {
  __shared__ u16 tile[32][33];
  int y = blockIdx.y;
  int t = threadIdx.x;
  if (y < 3) {
    const float* src = (y == 0) ? q : (y == 1) ? k : v;
    u16* dst = (y == 0) ? qb : (y == 1) ? kb : vb;
    int n4 = (y == 0) ? (B_ * NQ * CD / 4) : (B_ * NK * CD / 4);
    int i = blockIdx.x * 256 + t;
    if (i >= n4) return;
    float4 vv = ((const float4*)src)[i];
    ushort4 o;
    o.x = f2bf(vv.x); o.y = f2bf(vv.y); o.z = f2bf(vv.z); o.w = f2bf(vv.w);
    ((ushort4*)dst)[i] = o;
  } else {
    int x = blockIdx.x;
    if (x >= 4096) return;
    int which = x >> 10, xy = x & 1023;
    const float* src = (which == 0) ? W0 : (which == 1) ? W1 : (which == 2) ? W2 : W3;
    u16* dst = (which == 0) ? T0 : (which == 1) ? T1 : (which == 2) ? T2 : T3;
    int r0 = (xy >> 5) * 32, c0 = (xy & 31) * 32;
    int row = t >> 3, c4 = (t & 7) * 4;
    float4 vv = *(const float4*)&src[(r0 + row) * 1024 + c0 + c4];
    tile[row][c4 + 0] = f2bf(vv.x);
    tile[row][c4 + 1] = f2bf(vv.y);
    tile[row][c4 + 2] = f2bf(vv.z);
    tile[row][c4 + 3] = f2bf(vv.w);
    __syncthreads();
    ushort4 o;
    o.x = tile[c4 + 0][row];
    o.y = tile[c4 + 1][row];
    o.z = tile[c4 + 2][row];
    o.w = tile[c4 + 3][row];
    *(ushort4*)&dst[(c0 + row) * 1024 + r0 + c4] = o;
  }
}

// ---------- fused QKV projection GEMM + RoPE epilogue ----------
// (256,2): proven no-spill footprint. Split-K BK=64 staging: two BK=32
// sub-buffers filled by 8 GLL16 under ONE barrier pair -> half the
// vmcnt(0) barrier drains of the round-5 loop, same MFMA/ds_read totals.
__global__ __launch_bounds__(256, 2) void gemm_qkv(
    const u16* __restrict__ qb, const u16* __restrict__ kb, const u16* __restrict__ vb,
    const u16* __restrict__ wqt, const u16* __restrict__ wkt, const u16* __restrict__ wvt,
    const float* __restrict__ bq, const float* __restrict__ bk, const float* __restrict__ bv,
    u16* __restrict__ Qh, u16* __restrict__ Kh, u16* __restrict__ Vt) {
  __shared__ u16 As[2][128 * 32];
  __shared__ u16 Bs[2][128 * 32];
  const int z = blockIdx.z;
  if (z == 0 && blockIdx.y >= 32) return;  // Q has 4096 rows only
  const u16* A = (z == 0) ? qb : (z == 1) ? kb : vb;
  const u16* Bt = (z == 0) ? wqt : (z == 1) ? wkt : wvt;
  const float* bias = (z == 0) ? bq : (z == 1) ? bk : bv;
  const int BR = (z == 0) ? NQ : NK;  // rows per batch

  const int t = threadIdx.x;
  const int lane = t & 63, w = t >> 6;
  const int lc = lane & 15, lq = lane >> 4;
  const int m0 = blockIdx.y * 128, n0 = blockIdx.x * 128;
  const int wm = (w >> 1) * 64, wn = (w & 1) * 64;
  f32x4 acc[4][4] = {};
  const u16* ga = A + (m0 + (t >> 2)) * 1024 + (t & 3) * 8;
  const u16* gb = Bt + (n0 + (t >> 2)) * 1024 + (t & 3) * 8;
  char* lA0 = (char*)&As[0][0] + w * 1024;
  char* lA1 = (char*)&As[1][0] + w * 1024;
  char* lB0 = (char*)&Bs[0][0] + w * 1024;
  char* lB1 = (char*)&Bs[1][0] + w * 1024;
  const bool swap = (z < 2);
  for (int k0 = 0; k0 < 1024; k0 += 64) {
    if (k0) __syncthreads();
    GLL16(ga + k0, lA0);
    GLL16(ga + 64 * 1024 + k0, lA0 + 4096);
    GLL16(ga + k0 + 32, lA1);
    GLL16(ga + 64 * 1024 + k0 + 32, lA1 + 4096);
    GLL16(gb + k0, lB0);
    GLL16(gb + 64 * 1024 + k0, lB0 + 4096);
    GLL16(gb + k0 + 32, lB1);
    GLL16(gb + 64 * 1024 + k0 + 32, lB1 + 4096);
    __syncthreads();
#pragma unroll
    for (int kk = 0; kk < 2; ++kk) {
      bf16x8 af[4], bf[4];
#pragma unroll
      for (int i = 0; i < 4; ++i) {
        af[i] = *(const bf16x8*)&As[kk][(wm + i * 16 + lc) * 32 + lq * 8];
        bf[i] = *(const bf16x8*)&Bs[kk][(wn + i * 16 + lc) * 32 + lq * 8];
      }
      if (swap) {
        // acc[mi][ni] = (W row ni-block) x (A row mi-block): C^T layout
#pragma unroll
        for (int mi = 0; mi < 4; ++mi)
#pragma unroll
          for (int ni = 0; ni < 4; ++ni)
            acc[mi][ni] = __builtin_amdgcn_mfma_f32_16x16x32_bf16(bf[ni], af[mi], acc[mi][ni], 0, 0, 0);
      } else {
#pragma unroll
        for (int mi = 0; mi < 4; ++mi)
#pragma unroll
          for (int ni = 0; ni < 4; ++ni)
            acc[mi][ni] = __builtin_amdgcn_mfma_f32_16x16x32_bf16(af[mi], bf[ni], acc[mi][ni], 0, 0, 0);
      }
    }
  }

  if (swap) {
    // C^T layout: lane holds row = m0+wm+mi*16+lc, cols cb..cb+3 (in-lane rope pairs)
    u16* Out = (z == 0) ? Qh : Kh;
    const bool isQ = (z == 0);
#pragma unroll
    for (int ni = 0; ni < 4; ++ni) {
      int cb = n0 + wn + ni * 16 + lq * 4;
      float4 bv4 = *(const float4*)&bias[cb];
      int jj = (ni * 8 + lq * 2) & 15;  // pair idx mod 16 (ni<2: x-freqs, ni>=2: y-freqs)
      bool jl = ni < 2;
      float f0 = exp2f((float)jj * -NEGL2T);
      float f1 = f0 * FSTEP;
#pragma unroll
      for (int mi = 0; mi < 4; ++mi) {
        int row = m0 + wm + mi * 16 + lc;
        int bb = row >= BR ? 1 : 0;
        int tok = row - bb * BR;
        float v0 = acc[mi][ni][0] + bv4.x;
        float v1 = acc[mi][ni][1] + bv4.y;
        float v2 = acc[mi][ni][2] + bv4.z;
        float v3 = acc[mi][ni][3] + bv4.w;
        uint2 pk;
        if (isQ || tok < 2048) {
          float pos = jl ? (float)(tok & 63) : (float)(tok >> 6);
          float s0, c0, s1, c1;
          __sincosf(pos * f0, &s0, &c0);
          __sincosf(pos * f1, &s1, &c1);
          float o0 = v0 * c0 - v1 * s0, o1 = v0 * s0 + v1 * c0;
          float o2 = v2 * c1 - v3 * s1, o3 = v2 * s1 + v3 * c1;
          if (isQ) { o0 *= SC; o1 *= SC; o2 *= SC; o3 *= SC; }
          pk.x = pack2bf(o0, o1);
          pk.y = pack2bf(o2, o3);
        } else {
          pk.x = pack2bf(v0, v1);
          pk.y = pack2bf(v2, v3);
        }
        *(uint2*)&Out[row * 1024 + cb] = pk;
      }
    }
  } else {
    // V: normal layout: lane holds col, 4 consecutive toks -> one uint2 into Vt
#pragma unroll
    for (int ni = 0; ni < 4; ++ni) {
      int col = n0 + wn + ni * 16 + lc;
      float bv = bias[col];
      int hh = col >> 6, dd = col & 63;
#pragma unroll
      for (int mi = 0; mi < 4; ++mi) {
        int row0 = m0 + wm + mi * 16 + lq * 4;
        int bb = row0 >= NK ? 1 : 0;
        int tok0 = row0 - bb * NK;  // 4-row group never straddles the batch boundary
        uint2 pk;
        pk.x = pack2bf(acc[mi][ni][0] + bv, acc[mi][ni][1] + bv);
        pk.y = pack2bf(acc[mi][ni][2] + bv, acc[mi][ni][3] + bv);
        *(uint2*)&Vt[((bb * NH + hh) * HD + dd) * NK + tok0] = pk;
      }
    }
  }
}

// ---------- O projection: 128x64 tile, split-K BK=64 staging, f32x4 out ----------
__global__ __launch_bounds__(256, 2) void gemm_o(const u16* __restrict__ A,
                                                 const u16* __restrict__ Bt,
                                                 const float* __restrict__ bias,
                                                 float* __restrict__ Cout) {
  __shared__ u16 As[2][128 * 32];
  __shared__ u16 Bs[2][64 * 32];
  const int t = threadIdx.x;
  const int lane = t & 63, w = t >> 6;
  const int lc = lane & 15, lq = lane >> 4;
  const int m0 = blockIdx.y * 128, n0 = blockIdx.x * 64;
  const int wm = (w >> 1) * 64, wn = (w & 1) * 32;
  f32x4 acc[4][2] = {};
  const u16* ga = A + (m0 + (t >> 2)) * 1024 + (t & 3) * 8;
  const u16* gb = Bt + (n0 + (t >> 2)) * 1024 + (t & 3) * 8;
  char* lA0 = (char*)&As[0][0] + w * 1024;
  char* lA1 = (char*)&As[1][0] + w * 1024;
  char* lB0 = (char*)&Bs[0][0] + w * 1024;
  char* lB1 = (char*)&Bs[1][0] + w * 1024;
  for (int k0 = 0; k0 < 1024; k0 += 64) {
    if (k0) __syncthreads();
    GLL16(ga + k0, lA0);
    GLL16(ga + 64 * 1024 + k0, lA0 + 4096);
    GLL16(ga + k0 + 32, lA1);
    GLL16(ga + 64 * 1024 + k0 + 32, lA1 + 4096);
    GLL16(gb + k0, lB0);
    GLL16(gb + k0 + 32, lB1);
    __syncthreads();
#pragma unroll
    for (int kk = 0; kk < 2; ++kk) {
      bf16x8 af[4], bf[2];
#pragma unroll
      for (int i = 0; i < 4; ++i)
        af[i] = *(const bf16x8*)&As[kk][(wm + i * 16 + lc) * 32 + lq * 8];
#pragma unroll
      for (int i = 0; i < 2; ++i)
        bf[i] = *(const bf16x8*)&Bs[kk][(wn + i * 16 + lc) * 32 + lq * 8];
#pragma unroll
      for (int mi = 0; mi < 4; ++mi)
#pragma unroll
        for (int ni = 0; ni < 2; ++ni)
          acc[mi][ni] = __builtin_amdgcn_mfma_f32_16x16x32_bf16(bf[ni], af[mi], acc[mi][ni], 0, 0, 0);
    }
  }
#pragma unroll
  for (int ni = 0; ni < 2; ++ni) {
    int cb = n0 + wn + ni * 16 + lq * 4;
    float4 bv4 = *(const float4*)&bias[cb];
#pragma unroll
    for (int mi = 0; mi < 4; ++mi) {
      int row = m0 + wm + mi * 16 + lc;
      float4 o;
      o.x = acc[mi][ni][0] + bv4.x;
      o.y = acc[mi][ni][1] + bv4.y;
      o.z = acc[mi][ni][2] + bv4.z;
      o.w = acc[mi][ni][3] + bv4.w;
      *(float4*)&Cout[row * 1024 + cb] = o;
    }
  }
}

// ---------- flash attention: no-max softmax, S^T P-writes, K/V LDS double-buffer
#define LSTR 72
__global__ __launch_bounds__(256, 2) void attn_kernel(const u16* __restrict__ Qh,
                                                      const u16* __restrict__ Kh,
                                                      const u16* __restrict__ Vt,
                                                      u16* __restrict__ AO) {
  __shared__ u16 QPs[128 * LSTR];      // Q staging, then P[q][key] (wave-private rows)
  __shared__ u16 Ks[2 * 64 * LSTR];    // double-buffered
  __shared__ u16 Vs[2 * 64 * LSTR];    // transposed: [dd][key]
  const int t = threadIdx.x;
  const int lane = t & 63, w = t >> 6;
  const int lc = lane & 15, lq = lane >> 4;
  const int rr = lane >> 3, s = lane & 7;
  const int qt = blockIdx.x, h = blockIdx.y, b = blockIdx.z;

  {
    const u16* gq = Qh + (b * NQ + qt * 128 + w * 32 + rr) * CD + h * HD + s * 8;
    u16* lqp = &QPs[(w * 32 + rr) * LSTR + s * 8];
#pragma unroll
    for (int i = 0; i < 4; ++i)
      *(uint4*)(lqp + i * 8 * LSTR) = *(const uint4*)(gq + i * 8 * CD);
  }
  bf16x8 qf[2][2];
#pragma unroll
  for (int ni = 0; ni < 2; ++ni)
#pragma unroll
    for (int kk = 0; kk < 2; ++kk)
      qf[ni][kk] = *(const bf16x8*)&QPs[(w * 32 + ni * 16 + lc) * LSTR + kk * 32 + lq * 8];

  bf16x8 ones;
  {
    u32* op = (u32*)&ones;
    op[0] = op[1] = op[2] = op[3] = 0x3F803F80u;  // bf16 1.0 pairs
  }

  const u16* gK = Kh + (b * NK + w * 16 + rr) * CD + h * HD + s * 8;
  const u16* gV = Vt + ((b * NH + h) * HD + w * 16 + rr) * NK + s * 8;
  const int sk0 = (w * 16 + rr) * LSTR + s * 8;      // staging offsets in a buffer
  const int sk1 = (w * 16 + 8 + rr) * LSTR + s * 8;

  // prologue: tile0 -> buf0; issue tile1 loads
  uint4 kreg0 = *(const uint4*)(gK);
  uint4 kreg1 = *(const uint4*)(gK + 8 * CD);
  uint4 vreg0 = *(const uint4*)(gV);
  uint4 vreg1 = *(const uint4*)(gV + 8 * NK);
  *(uint4*)&Ks[sk0] = kreg0;
  *(uint4*)&Ks[sk1] = kreg1;
  *(uint4*)&Vs[sk0] = vreg0;
  *(uint4*)&Vs[sk1] = vreg1;
  kreg0 = *(const uint4*)(gK + 64 * CD);
  kreg1 = *(const uint4*)(gK + 64 * CD + 8 * CD);
  vreg0 = *(const uint4*)(gV + 64);
  vreg1 = *(const uint4*)(gV + 8 * NK + 64);
  __syncthreads();

  f32x4 oacc[2][4] = {};
  f32x4 lacc[2] = {};
  int p = 0;

  for (int j0 = 0; j0 < NK; j0 += 64) {
    const u16* Kc = &Ks[p * 64 * LSTR];

    f32x4 st[2][4] = {};
#pragma unroll
    for (int mi = 0; mi < 4; ++mi) {
      bf16x8 k0f = *(const bf16x8*)&Kc[(mi * 16 + lc) * LSTR + lq * 8];
      bf16x8 k1f = *(const bf16x8*)&Kc[(mi * 16 + lc) * LSTR + 32 + lq * 8];
#pragma unroll
      for (int ni = 0; ni < 2; ++ni) {
        st[ni][mi] = __builtin_amdgcn_mfma_f32_16x16x32_bf16(k0f, qf[ni][0], st[ni][mi], 0, 0, 0);
        st[ni][mi] = __builtin_amdgcn_mfma_f32_16x16x32_bf16(k1f, qf[ni][1], st[ni][mi], 0, 0, 0);
      }
    }
#pragma unroll
    for (int ni = 0; ni < 2; ++ni)
#pragma unroll
      for (int mi = 0; mi < 4; ++mi) {
        u32 e0 = __float_as_uint(__builtin_amdgcn_exp2f(st[ni][mi][0]));
        u32 e1 = __float_as_uint(__builtin_amdgcn_exp2f(st[ni][mi][1]));
        u32 e2 = __float_as_uint(__builtin_amdgcn_exp2f(st[ni][mi][2]));
        u32 e3 = __float_as_uint(__builtin_amdgcn_exp2f(st[ni][mi][3]));
        uint2 pk;
        pk.x = __builtin_amdgcn_perm(e1 + 0x8000u, e0 + 0x8000u, 0x07060302u);
        pk.y = __builtin_amdgcn_perm(e3 + 0x8000u, e2 + 0x8000u, 0x07060302u);
        *(uint2*)&QPs[(w * 32 + ni * 16 + lc) * LSTR + mi * 16 + lq * 4] = pk;
      }
#pragma unroll
    for (int kc = 0; kc < 2; ++kc) {
      bf16x8 pf[2], vf[4];
#pragma unroll
      for (int ni = 0; ni < 2; ++ni)
        pf[ni] = *(const bf16x8*)&QPs[(w * 32 + ni * 16 + lc) * LSTR + kc * 32 + lq * 8];
#pragma unroll
      for (int di = 0; di < 4; ++di)
        vf[di] = *(const bf16x8*)&Vs[p * 64 * LSTR + (di * 16 + lc) * LSTR + kc * 32 + lq * 8];
#pragma unroll
      for (int ni = 0; ni < 2; ++ni) {
#pragma unroll
        for (int di = 0; di < 4; ++di)
          oacc[ni][di] = __builtin_amdgcn_mfma_f32_16x16x32_bf16(pf[ni], vf[di], oacc[ni][di], 0, 0, 0);
        lacc[ni] = __builtin_amdgcn_mfma_f32_16x16x32_bf16(pf[ni], ones, lacc[ni], 0, 0, 0);
      }
    }

    if (j0 + 64 < NK) {
      // store tile j+1 into the idle buffer (vmcnt wait was hidden by compute)
      u16* Kn = &Ks[(p ^ 1) * 64 * LSTR];
      u16* Vn = &Vs[(p ^ 1) * 64 * LSTR];
      *(uint4*)&Kn[sk0] = kreg0;
      *(uint4*)&Kn[sk1] = kreg1;
      *(uint4*)&Vn[sk0] = vreg0;
      *(uint4*)&Vn[sk1] = vreg1;
      if (j0 + 128 < NK) {  // issue tile j+2 loads
        kreg0 = *(const uint4*)(gK + (j0 + 128) * CD);
        kreg1 = *(const uint4*)(gK + (j0 + 128) * CD + 8 * CD);
        vreg0 = *(const uint4*)(gV + j0 + 128);
        vreg1 = *(const uint4*)(gV + 8 * NK + j0 + 128);
      }
    }
    __syncthreads();
    p ^= 1;
  }
#pragma unroll
  for (int ni = 0; ni < 2; ++ni)
#pragma unroll
    for (int r = 0; r < 4; ++r) {
      float inv = 1.0f / lacc[ni][r];
#pragma unroll
      for (int di = 0; di < 4; ++di) {
        int row = qt * 128 + w * 32 + ni * 16 + lq * 4 + r;
        int col = h * HD + di * 16 + lc;
        AO[(b * NQ + row) * CD + col] = f2bf(oacc[ni][di][r] * inv);
      }
    }
}

extern "C" void kernel_launch(void* const* d_in, const int* in_sizes, int n_in,
                              void* d_out, int out_size, void* d_ws, size_t ws_size,
                              hipStream_t stream) {
  const float* q  = (const float*)d_in[0];
  const float* k  = (const float*)d_in[1];
  const float* v  = (const float*)d_in[2];
  const float* Wq = (const float*)d_in[3];
  const float* bq = (const float*)d_in[4];
  const float* Wk = (const float*)d_in[5];
  const float* bk = (const float*)d_in[6];
  const float* Wv = (const float*)d_in[7];
  const float* bv = (const float*)d_in[8];
  const float* Wo = (const float*)d_in[9];
  const float* bo = (const float*)d_in[10];

  char* ws = (char*)d_ws;
  size_t off = 0;
  auto alloc = [&](size_t bytes) {
    char* p = ws + off;
    off += (bytes + 255) & ~(size_t)255;
    return p;
  };
  u16* qb  = (u16*)alloc((size_t)B_ * NQ * CD * 2);
  u16* kb  = (u16*)alloc((size_t)B_ * NK * CD * 2);
  u16* vb  = (u16*)alloc((size_t)B_ * NK * CD * 2);
  u16* wqt = (u16*)alloc((size_t)CD * CD * 2);
  u16* wkt = (u16*)alloc((size_t)CD * CD * 2);
  u16* wvt = (u16*)alloc((size_t)CD * CD * 2);
  u16* wot = (u16*)alloc((size_t)CD * CD * 2);
  u16* Qh  = (u16*)alloc((size_t)B_ * NQ * CD * 2);
  u16* Kh  = (u16*)alloc((size_t)B_ * NK * CD * 2);
  u16* Vt  = (u16*)alloc((size_t)B_ * NK * CD * 2);
  u16* AO  = (u16*)alloc((size_t)B_ * NQ * CD * 2);

  prep_kernel<<<dim3(4224, 4), 256, 0, stream>>>(q, k, v, qb, kb, vb,
                                                 Wq, Wk, Wv, Wo, wqt, wkt, wvt, wot);
  gemm_qkv<<<dim3(8, 33, 3), 256, 0, stream>>>(qb, kb, vb, wqt, wkt, wvt, bq, bk, bv, Qh, Kh, Vt);
  attn_kernel<<<dim3(16, NH, B_), 256, 0, stream>>>(Qh, Kh, Vt, AO);
  gemm_o<<<dim3(16, 32), 256, 0, stream>>>(AO, wot, bo, (float*)d_out);
}